// Round 10
// baseline (1493.374 us; speedup 1.0000x reference)
//
#include <hip/hip_runtime.h>

#define DD 300
#define KP 320          // padded K (10 chunks of 32)
#define NT 19           // n-tiles of 16 (covers 304)
#define NCH 10          // k-chunks
#define PLANE_SH 9728   // shorts per LDS plane: 304 rows x 32 k
#define BUF_SH 19456    // shorts: hi + lo planes (38912 B)

typedef __attribute__((ext_vector_type(8))) short short8;
typedef __attribute__((ext_vector_type(4))) float f32x4;

__device__ __forceinline__ unsigned short bf16_rne(float x) {
    union { float f; unsigned u; } v; v.f = x;
    v.u += 0x7FFF + ((v.u >> 16) & 1);
    return (unsigned short)(v.u >> 16);
}
__device__ __forceinline__ float bf16_to_f32(unsigned short h) {
    union { unsigned u; float f; } v; v.u = (unsigned)h << 16;
    return v.f;
}

// split Wl (n,k == B-frag layout) into padded bf16 hi/lo planes [KP][KP]
__global__ void split_w(const float* __restrict__ Wl, short* __restrict__ Whi, short* __restrict__ Wlo) {
    int idx = blockIdx.x * 256 + threadIdx.x;
    if (idx >= KP * KP) return;
    int n = idx / KP, k = idx % KP;
    float v = (n < DD && k < DD) ? Wl[n * DD + k] : 0.f;
    unsigned short hi = bf16_rne(v);
    Whi[idx] = (short)hi;
    Wlo[idx] = (short)bf16_rne(v - bf16_to_f32(hi));
}

// ---- level-0 projection (gather): one wave per row (round-7 proven) ----
__global__ __launch_bounds__(256) void proj0_kernel(
    const float* __restrict__ emb, const int* __restrict__ ids,
    const float* __restrict__ Wp, const float* __restrict__ bp,
    float* __restrict__ out, int M)
{
    int wave = (blockIdx.x * 256 + threadIdx.x) >> 6;
    int lane = threadIdx.x & 63;
    if (wave >= M) return;
    const float* row = emb + (size_t)ids[wave] * DD;
    float x0 = row[lane], x1 = row[lane + 64], x2 = row[lane + 128], x3 = row[lane + 192];
    float x4 = 0.f, wa = 0.f, wb = 0.f, wc = 0.f;
    if (lane < 44) {
        x4 = row[lane + 256];
        wa = Wp[lane + 256]; wb = Wp[DD + lane + 256]; wc = Wp[2 * DD + lane + 256];
    }
    float a0 = x0 * Wp[lane] + x1 * Wp[lane + 64] + x2 * Wp[lane + 128] + x3 * Wp[lane + 192] + x4 * wa;
    float a1 = x0 * Wp[DD + lane] + x1 * Wp[DD + lane + 64] + x2 * Wp[DD + lane + 128] + x3 * Wp[DD + lane + 192] + x4 * wb;
    float a2 = x0 * Wp[2 * DD + lane] + x1 * Wp[2 * DD + lane + 64] + x2 * Wp[2 * DD + lane + 128] + x3 * Wp[2 * DD + lane + 192] + x4 * wc;
    #pragma unroll
    for (int off = 32; off > 0; off >>= 1) {
        a0 += __shfl_down(a0, off);
        a1 += __shfl_down(a1, off);
        a2 += __shfl_down(a2, off);
    }
    if (lane == 0) {
        int b = wave >> 12, n = wave & 4095;
        float* o = out + ((size_t)b * 8191 + n) * 3;
        o[0] = a0 + bp[0];
        o[1] = a1 + bp[1];
        o[2] = a2 + bp[2];
    }
}

// Fused tree kernel via pair-sum relay: each level runs the R7-proven GEMM body,
// fused projection (pjb LDS reduce), and writes the NEXT level's input s = h[2j]+h[2j+1]
// (in-lane register pair, f32) to a FRESH per-block global buffer. No h anywhere.
// lv=0: pairmode (ids gather) or direct s rows (dispatch B reads s8 bridge).
__global__ __launch_bounds__(256, 2) void tree_fused(
    const float* __restrict__ src, const int* __restrict__ ids,
    const short* __restrict__ Whi, const short* __restrict__ Wlo,
    const float* __restrict__ bl, const float* __restrict__ Wp, const float* __restrict__ bp,
    float* __restrict__ out, float* __restrict__ sScratch, float* __restrict__ bridge,
    int baseLevel, int nlev)
{
    __shared__ __align__(16) short wbuf[BUF_SH];   // W chunk; reused as pj scratch per level
    int tid = threadIdx.x;
    int wid = tid >> 6, lane = tid & 63;
    int r = lane & 15, q = lane >> 4;
    float* blockS = sScratch + (long)blockIdx.x * 128 * DD;   // fresh rows, 126 used

    // stage one 32-k chunk of both planes into LDS (R7 proven)
    auto stage = [&](int c) {
        for (int s = wid; s < 2 * NT; s += 4) {
            int pl = s >= NT ? 1 : 0;
            int ss = s - pl * NT;
            const short* gpl = pl ? Wlo : Whi;
            short8 v = *(const short8*)(gpl + (long)(ss * 16 + (lane >> 2)) * KP + c * 32 + (lane & 3) * 8);
            *(short8*)&wbuf[pl * PLANE_SH + ss * 512 + lane * 8] = v;
        }
    };

    #pragma unroll 1
    for (int lv = 0; lv < nlev; ++lv) {
        int lev = baseLevel + lv;
        int Mloc = 128 >> lv;          // this level's output rows per block
        int Shalf = Mloc >> 1;         // next level's input rows per block
        bool pairmode = (lv == 0) && (ids != nullptr);

        int mA = wid * 32 + r, mB = mA + 16;       // local output rows (tiles A, B)
        int mAc = mA < Mloc ? mA : 0;
        int mBc = mB < Mloc ? mB : 0;
        const float *p0, *p1, *p2, *p3;
        if (lv == 0) {
            long g0 = (long)blockIdx.x * 128 + mAc;
            long g1 = (long)blockIdx.x * 128 + mBc;
            if (pairmode) {
                p0 = src + (long)ids[2 * g0] * DD; p1 = src + (long)ids[2 * g0 + 1] * DD;
                p2 = src + (long)ids[2 * g1] * DD; p3 = src + (long)ids[2 * g1 + 1] * DD;
            } else {
                p0 = src + g0 * DD; p1 = p0;
                p2 = src + g1 * DD; p3 = p2;
            }
        } else {
            const float* sprev = blockS + (long)(128 - (128 >> (lv - 1))) * DD;
            p0 = sprev + (long)mAc * DD; p1 = p0;
            p2 = sprev + (long)mBc * DD; p3 = p2;
        }
        float* dstS; bool writeS;
        if (lv < nlev - 1)  { dstS = blockS + (long)(128 - (128 >> lv)) * DD; writeS = true; }
        else if (bridge)    { dstS = bridge + (long)blockIdx.x * Shalf * DD;  writeS = true; }  // lev==7, Shalf==1
        else                { dstS = nullptr; writeS = false; }

        auto loadx = [&](int c, f32x4* x) {
            int kk = c * 32 + q * 8;
            if (kk + 8 <= DD) {
                x[0] = *(const f32x4*)(p0 + kk); x[1] = *(const f32x4*)(p0 + kk + 4);
                x[4] = *(const f32x4*)(p2 + kk); x[5] = *(const f32x4*)(p2 + kk + 4);
                if (pairmode) {
                    x[2] = *(const f32x4*)(p1 + kk); x[3] = *(const f32x4*)(p1 + kk + 4);
                    x[6] = *(const f32x4*)(p3 + kk); x[7] = *(const f32x4*)(p3 + kk + 4);
                }
            } else {
                #pragma unroll
                for (int i = 0; i < 8; ++i) {
                    int kg = kk + i; bool ok = kg < DD;
                    x[0 + (i >> 2)][i & 3] = ok ? p0[kg] : 0.f;
                    x[4 + (i >> 2)][i & 3] = ok ? p2[kg] : 0.f;
                    if (pairmode) {
                        x[2 + (i >> 2)][i & 3] = ok ? p1[kg] : 0.f;
                        x[6 + (i >> 2)][i & 3] = ok ? p3[kg] : 0.f;
                    }
                }
            }
        };

        f32x4 acc0[NT] = {};
        f32x4 acc1[NT] = {};
        f32x4 xc[8], xn[8];
        loadx(0, xc);

        #pragma unroll 1
        for (int c = 0; c < NCH; ++c) {
            __syncthreads();                        // wbuf free (prev reads done)
            stage(c);
            __syncthreads();                        // chunk c staged & visible
            if (c + 1 < NCH) loadx(c + 1, xn);

            f32x4 sA0, sA1, sB0, sB1;
            if (pairmode) { sA0 = xc[0] + xc[2]; sA1 = xc[1] + xc[3]; sB0 = xc[4] + xc[6]; sB1 = xc[5] + xc[7]; }
            else          { sA0 = xc[0];         sA1 = xc[1];         sB0 = xc[4];         sB1 = xc[5]; }
            short8 xhi, xlo, yhi, ylo;
            #pragma unroll
            for (int i = 0; i < 4; ++i) {
                unsigned short h; float v;
                v = sA0[i]; h = bf16_rne(v); xhi[i]     = (short)h; xlo[i]     = (short)bf16_rne(v - bf16_to_f32(h));
                v = sA1[i]; h = bf16_rne(v); xhi[4 + i] = (short)h; xlo[4 + i] = (short)bf16_rne(v - bf16_to_f32(h));
                v = sB0[i]; h = bf16_rne(v); yhi[i]     = (short)h; ylo[i]     = (short)bf16_rne(v - bf16_to_f32(h));
                v = sB1[i]; h = bf16_rne(v); yhi[4 + i] = (short)h; ylo[4 + i] = (short)bf16_rne(v - bf16_to_f32(h));
            }
            const short* bhp = &wbuf[r * 32 + q * 8];
            const short* bop = bhp + PLANE_SH;
            #pragma unroll
            for (int t = 0; t < NT; ++t) {
                short8 bh = *(const short8*)(bhp + t * 512);
                short8 bo = *(const short8*)(bop + t * 512);
                acc0[t] = __builtin_amdgcn_mfma_f32_16x16x32_bf16(xhi, bh, acc0[t], 0, 0, 0);
                acc0[t] = __builtin_amdgcn_mfma_f32_16x16x32_bf16(xhi, bo, acc0[t], 0, 0, 0);
                acc0[t] = __builtin_amdgcn_mfma_f32_16x16x32_bf16(xlo, bh, acc0[t], 0, 0, 0);
                acc1[t] = __builtin_amdgcn_mfma_f32_16x16x32_bf16(yhi, bh, acc1[t], 0, 0, 0);
                acc1[t] = __builtin_amdgcn_mfma_f32_16x16x32_bf16(yhi, bo, acc1[t], 0, 0, 0);
                acc1[t] = __builtin_amdgcn_mfma_f32_16x16x32_bf16(ylo, bh, acc1[t], 0, 0, 0);
            }
            if (c + 1 < NCH) {
                #pragma unroll
                for (int i = 0; i < 8; ++i) xc[i] = xn[i];
            }
        }

        // epilogue: bias + ReLU + pj partials + s-writes (pair sums, in-lane)
        float pj[2][4][3] = {};
        #pragma unroll
        for (int t = 0; t < NT; ++t) {
            int n = t * 16 + r;
            bool nok = n < DD;
            float w0 = nok ? Wp[n] : 0.f;
            float w1 = nok ? Wp[DD + n] : 0.f;
            float w2 = nok ? Wp[2 * DD + n] : 0.f;
            float b2 = nok ? 2.f * bl[n] : 0.f;
            float v0a = acc0[t][0] + b2; v0a = v0a > 0.f ? v0a : 0.f;
            float v0b = acc0[t][1] + b2; v0b = v0b > 0.f ? v0b : 0.f;
            float v0c = acc0[t][2] + b2; v0c = v0c > 0.f ? v0c : 0.f;
            float v0d = acc0[t][3] + b2; v0d = v0d > 0.f ? v0d : 0.f;
            float v1a = acc1[t][0] + b2; v1a = v1a > 0.f ? v1a : 0.f;
            float v1b = acc1[t][1] + b2; v1b = v1b > 0.f ? v1b : 0.f;
            float v1c = acc1[t][2] + b2; v1c = v1c > 0.f ? v1c : 0.f;
            float v1d = acc1[t][3] + b2; v1d = v1d > 0.f ? v1d : 0.f;
            pj[0][0][0] += v0a * w0; pj[0][0][1] += v0a * w1; pj[0][0][2] += v0a * w2;
            pj[0][1][0] += v0b * w0; pj[0][1][1] += v0b * w1; pj[0][1][2] += v0b * w2;
            pj[0][2][0] += v0c * w0; pj[0][2][1] += v0c * w1; pj[0][2][2] += v0c * w2;
            pj[0][3][0] += v0d * w0; pj[0][3][1] += v0d * w1; pj[0][3][2] += v0d * w2;
            pj[1][0][0] += v1a * w0; pj[1][0][1] += v1a * w1; pj[1][0][2] += v1a * w2;
            pj[1][1][0] += v1b * w0; pj[1][1][1] += v1b * w1; pj[1][1][2] += v1b * w2;
            pj[1][2][0] += v1c * w0; pj[1][2][1] += v1c * w1; pj[1][2][2] += v1c * w2;
            pj[1][3][0] += v1d * w0; pj[1][3][1] += v1d * w1; pj[1][3][2] += v1d * w2;
            if (writeS && nok) {
                int s0r = wid * 16 + 2 * q;         // s row for pair (q*4+0, q*4+1)
                if (s0r < Shalf)     dstS[(long)s0r * DD + n]       = v0a + v0b;
                if (s0r + 1 < Shalf) dstS[(long)(s0r + 1) * DD + n] = v0c + v0d;
                if (s0r + 8 < Shalf) dstS[(long)(s0r + 8) * DD + n] = v1a + v1b;
                if (s0r + 9 < Shalf) dstS[(long)(s0r + 9) * DD + n] = v1c + v1d;
            }
        }
        // projection reduce over the 16 r-lanes via LDS (R7 proven)
        __syncthreads();                            // wbuf K-reads done
        float* pjb = (float*)wbuf;
        #pragma unroll
        for (int h = 0; h < 2; ++h)
            #pragma unroll
            for (int g = 0; g < 4; ++g)
                #pragma unroll
                for (int cc = 0; cc < 3; ++cc)
                    pjb[(wid * 32 + h * 16 + q * 4 + g) * 48 + r * 3 + cc] = pj[h][g][cc];
        __syncthreads();
        if (tid < Mloc) {
            const float* base = &pjb[tid * 48];
            float s0 = 0.f, s1 = 0.f, s2 = 0.f;
            #pragma unroll
            for (int rr = 0; rr < 16; ++rr) {
                s0 += base[rr * 3]; s1 += base[rr * 3 + 1]; s2 += base[rr * 3 + 2];
            }
            int m = blockIdx.x * Mloc + tid;
            int lg = 12 - lev;
            int offk = 8192 - (8192 >> lev);
            float* o = out + ((size_t)(m >> lg) * 8191 + offk + (m & ((1 << lg) - 1))) * 3;
            o[0] = s0 + bp[0]; o[1] = s1 + bp[1]; o[2] = s2 + bp[2];
        }
        __threadfence_block();                      // drain s-stores (vmcnt) ...
        __syncthreads();                            // ... and order across waves before next level reads
    }
}

extern "C" void kernel_launch(void* const* d_in, const int* in_sizes, int n_in,
                              void* d_out, int out_size, void* d_ws, size_t ws_size,
                              hipStream_t stream)
{
    const int*   word_ids  = (const int*)d_in[0];    // (32, 4096) int32
    const float* embedding = (const float*)d_in[1];  // (50000, 300) f32
    const float* Wl        = (const float*)d_in[2];  // (300, 300) f32
    const float* bl        = (const float*)d_in[3];  // (300,) f32
    const float* Wp        = (const float*)d_in[4];  // (3, 300) f32
    const float* bp        = (const float*)d_in[5];  // (3,) f32
    float* out = (float*)d_out;

    // ws: sScratchA (512 blk x 128 rows) | sScratchB (4 x 128) | s8 bridge (512 rows) | Whi | Wlo
    char* ws = (char*)d_ws;
    float* sA  = (float*)ws;                                   // 78,643,200 B
    float* sB  = (float*)(ws + 78643200);                      //    614,400 B
    float* s8  = (float*)(ws + 78643200 + 614400);             //    614,400 B
    short* Whi = (short*)(ws + 78643200 + 614400 + 614400);
    short* Wlo = Whi + KP * KP;

    split_w<<<(KP * KP + 255) / 256, 256, 0, stream>>>(Wl, Whi, Wlo);

    // level 0 projection straight off the gather (h0 never materialized)
    int M0 = 32 * 4096;
    proj0_kernel<<<(M0 + 3) / 4, 256, 0, stream>>>(embedding, word_ids, Wp, bp, out, M0);

    // levels 1..7: 512 blocks x 128 level-1 rows, block-local tree, writes s8 bridge
    tree_fused<<<512, 256, 0, stream>>>(embedding, word_ids, Whi, Wlo, bl, Wp, bp,
                                        out, sA, s8, 1, 7);
    // levels 8..12: 4 blocks x 128 level-8 rows, reads s8 directly (pre-summed)
    tree_fused<<<4, 256, 0, stream>>>(s8, nullptr, Whi, Wlo, bl, Wp, bp,
                                      out, sB, nullptr, 8, 5);
}